// Round 2
// baseline (1451.059 us; speedup 1.0000x reference)
//
#include <hip/hip_runtime.h>
#include <hip/hip_bf16.h>

typedef short short8 __attribute__((ext_vector_type(8)));
typedef float floatx4 __attribute__((ext_vector_type(4)));
typedef unsigned short ushort_t;

// Problem constants
#define NB   4
#define NC_X 64     // x channels == out channels (DIM)
#define NC_C 128    // context channels
#define ND   64
#define NHW  4096   // H*W
#define NH   64
#define NW   64
#define NS   (NB * ND)   // 256 (b,d) slices total

// f32 -> bf16 round-to-nearest-even (inputs finite)
__device__ __forceinline__ ushort_t f2bf(float f) {
    unsigned u;
    __builtin_memcpy(&u, &f, 4);
    u += 0x7fffu + ((u >> 16) & 1u);
    return (ushort_t)(u >> 16);
}

// async global->LDS, 16B per lane; LDS dest = uniform base + lane*16 (linear)
__device__ __forceinline__ void gld_lds16(const void* g, void* l) {
    __builtin_amdgcn_global_load_lds(
        (const __attribute__((address_space(1))) unsigned int*)g,
        (__attribute__((address_space(3))) unsigned int*)l, 16, 0, 0);
}

// ---------------------------------------------------------------------------
// prep: convert weights to bf16 (fold softmax scale 1/8 into wq,bq), stash in ws
// wW layout: [0,4096) = wq[oc][ic] (64x64, scaled)
//            [4096, 20480) = wkv[row][ic] (128x128): rows 0..63 = wk, 64..127 = wv
// wB: f32 [192]: bq*0.125 | bk | bv
// ---------------------------------------------------------------------------
__global__ void prep_kernel(const float* __restrict__ wq, const float* __restrict__ bq,
                            const float* __restrict__ wk, const float* __restrict__ bk,
                            const float* __restrict__ wv, const float* __restrict__ bv,
                            ushort_t* __restrict__ wW, float* __restrict__ wB) {
    int t = blockIdx.x * blockDim.x + threadIdx.x;
    int N = gridDim.x * blockDim.x;
    for (int i = t; i < 4096; i += N) wW[i] = f2bf(wq[i] * 0.125f);
    for (int i = t; i < 8192; i += N) wW[4096 + i] = f2bf(wk[i]);
    for (int i = t; i < 8192; i += N) wW[12288 + i] = f2bf(wv[i]);
    for (int i = t; i < 64; i += N) {
        wB[i] = bq[i] * 0.125f;
        wB[64 + i] = bk[i];
        wB[128 + i] = bv[i];
    }
}

// ---------------------------------------------------------------------------
// proj v2: glds-staged f32 tiles, transposed ds_read_b32 + f2bf on read.
// Block: 256 thr = 4 waves; handles (slice, 64-hw chunk). Grid (64, w).
//
// LDS logical layout (f32, LINEAR for glds): elem (ic, hw) at word
//   ic*64 + ((hw>>2) ^ sw(ic))*4 + (hw&3),  sw(ic) = ((ic>>3)&3)<<1
// The granule XOR is realized by permuting the per-lane GLOBAL source address
// (glds dest must stay linear); reads apply the same XOR. 2-way banks = free.
// ---------------------------------------------------------------------------
__global__ __launch_bounds__(256, 3)
void proj_kernel(const float* __restrict__ x, const float* __restrict__ ctx,
                 const ushort_t* __restrict__ wW, const float* __restrict__ wB,
                 ushort_t* __restrict__ qws, ushort_t* __restrict__ kws,
                 ushort_t* __restrict__ vws, int s0, int nd) {
    __shared__ float XF[64 * 64];      // x tile   [64 ic][64 hw]  16 KB
    __shared__ float CF[128 * 64];     // ctx tile [128 ic][64 hw] 32 KB

    const int t = threadIdx.x;
    const int si = blockIdx.y;
    const int s = s0 + si;
    const int b = s >> 6;
    const int d = s & 63;
    const int hw0 = blockIdx.x * 64;

    const float* xb = x + ((size_t)(b * NC_X) * ND + d) * NHW + hw0;   // + ic*(ND*NHW) + hw
    const float* cb = ctx + ((size_t)(b * NC_C) * ND + d) * NHW + hw0;

    const int wv = t >> 6, lane = t & 63, l15 = lane & 15, quad = lane >> 4;

    // ---- stage: 48 glds chunks (1 KB each): 16 for X, 32 for CTX; 12 per wave
    {
        const int lr = lane >> 4;          // ic sub-row within chunk
        const int gs = lane & 15;          // granule slot within row
        #pragma unroll
        for (int i = 0; i < 12; ++i) {
            const int k = wv * 12 + i;     // wave-uniform
            if (k < 16) {
                const int ic = k * 4 + lr;
                const int g = gs ^ (((ic >> 3) & 3) << 1);   // inverse == forward (XOR)
                gld_lds16(xb + ((size_t)ic << 18) + g * 4, &XF[k * 256]);
            } else {
                const int kc = k - 16;
                const int ic = kc * 4 + lr;
                const int g = gs ^ (((ic >> 3) & 3) << 1);
                gld_lds16(cb + ((size_t)ic << 18) + g * 4, &CF[kc * 256]);
            }
        }
    }
    __syncthreads();

    const floatx4 zero4 = {0.f, 0.f, 0.f, 0.f};
    const int lo = l15 & 3;
    const int hb = wv * 4 + (l15 >> 2);    // (hw>>2) for this lane's column

    // ================= Q = Wq(64x64) * X(64x64cols) =================
    short8 aQ[4][2];
    #pragma unroll
    for (int mt = 0; mt < 4; ++mt)
        #pragma unroll
        for (int kk = 0; kk < 2; ++kk)
            aQ[mt][kk] = *(const short8*)&wW[(mt * 16 + l15) * 64 + kk * 32 + quad * 8];

    floatx4 acc[4];
    #pragma unroll
    for (int mt = 0; mt < 4; ++mt) acc[mt] = zero4;

    #pragma unroll
    for (int kk = 0; kk < 2; ++kk) {
        const int sw = ((kk * 4 + quad) & 3) << 1;
        const float* bb = &XF[(kk * 32 + quad * 8) * 64 + (hb ^ sw) * 4 + lo];
        short8 bX;
        #pragma unroll
        for (int j = 0; j < 8; ++j) bX[j] = (short)f2bf(bb[j * 64]);
        #pragma unroll
        for (int mt = 0; mt < 4; ++mt)
            acc[mt] = __builtin_amdgcn_mfma_f32_16x16x32_bf16(aQ[mt][kk], bX, acc[mt], 0, 0, 0);
    }
    {
        const int col = hw0 + wv * 16 + l15;
        #pragma unroll
        for (int mt = 0; mt < 4; ++mt)
            #pragma unroll
            for (int r = 0; r < 4; ++r) {
                const int oc = mt * 16 + quad * 4 + r;
                qws[((size_t)(oc * nd + si)) * NHW + col] = f2bf(acc[mt][r] + wB[oc]);
            }
    }

    // ================= [K;V] = Wkv(128x128) * CTX(128x64cols) =================
    floatx4 acc2[8];
    #pragma unroll
    for (int mt = 0; mt < 8; ++mt) acc2[mt] = zero4;

    #pragma unroll
    for (int kk = 0; kk < 4; ++kk) {
        const int sw = ((kk * 4 + quad) & 3) << 1;
        const float* bb = &CF[(kk * 32 + quad * 8) * 64 + (hb ^ sw) * 4 + lo];
        short8 bC;
        #pragma unroll
        for (int j = 0; j < 8; ++j) bC[j] = (short)f2bf(bb[j * 64]);
        #pragma unroll
        for (int mt = 0; mt < 8; ++mt) {
            const short8 aW =
                *(const short8*)&wW[4096 + (mt * 16 + l15) * 128 + kk * 32 + quad * 8];
            acc2[mt] = __builtin_amdgcn_mfma_f32_16x16x32_bf16(aW, bC, acc2[mt], 0, 0, 0);
        }
    }
    {
        const int col = hw0 + wv * 16 + l15;
        #pragma unroll
        for (int mt = 0; mt < 8; ++mt)
            #pragma unroll
            for (int r = 0; r < 4; ++r) {
                const int row = mt * 16 + quad * 4 + r;     // 0..63 = K oc, 64..127 = V oc
                const float val = acc2[mt][r] + wB[64 + row];
                ushort_t* dst = (row < 64) ? kws : vws;
                dst[((size_t)((row & 63) * nd + si)) * NHW + col] = f2bf(val);
            }
    }
}

// ---------------------------------------------------------------------------
// attn: per (c, si) 64x64 slice: S = Qs*K^T, softmax rows, O = P*V / l + x
// Block 256 thr; wave w owns rows [16w,16w+16). Grid (64, w).
// V staged via 2x b128 global loads/thread -> LDS natural -> LDS transpose.
// ---------------------------------------------------------------------------
__global__ __launch_bounds__(256, 3)
void attn_kernel(const ushort_t* __restrict__ qws, const ushort_t* __restrict__ kws,
                 const ushort_t* __restrict__ vws, const float* __restrict__ x,
                 float* __restrict__ out, int s0, int nd) {
    __shared__ ushort_t Vn[64][72];   // V natural: Vn[g][w]
    __shared__ ushort_t Vs[64][72];   // V transposed: Vs[w][g]
    __shared__ ushort_t Ps[64][72];   // P (unnormalized exp), row-major

    const int c = blockIdx.x, si = blockIdx.y;
    const int s = s0 + si;
    const int b = s >> 6;
    const int d = s & 63;
    const ushort_t* qp = qws + (size_t)(c * nd + si) * NHW;
    const ushort_t* kp = kws + (size_t)(c * nd + si) * NHW;
    const ushort_t* vp = vws + (size_t)(c * nd + si) * NHW;
    const float* xp = x + ((size_t)(b * NC_X + c) * ND + d) * NHW;
    float* op = out + ((size_t)(b * NC_X + c) * ND + d) * NHW;

    const int t = threadIdx.x;
    const int wv = t >> 6, lane = t & 63, l15 = lane & 15, quad = lane >> 4;

    // ---- issue ALL global loads up front (max bytes in flight) ----
    // V: 2 x b128 per thread (natural layout rows)
    short8 vreg[2];
    int vg[2], vw0[2];
    #pragma unroll
    for (int i = 0; i < 2; ++i) {
        const int ch = t + i * 256;           // 512 chunks of 8 ushorts
        vg[i] = ch >> 3;
        vw0[i] = (ch & 7) * 8;
        vreg[i] = *(const short8*)&vp[vg[i] * NW + vw0[i]];
    }
    // Q, K fragments (b128)
    short8 aQ[2], bK[4][2];
    #pragma unroll
    for (int kk = 0; kk < 2; ++kk)
        aQ[kk] = *(const short8*)&qp[(wv * 16 + l15) * NW + kk * 32 + quad * 8];
    #pragma unroll
    for (int nt = 0; nt < 4; ++nt)
        #pragma unroll
        for (int kk = 0; kk < 2; ++kk)
            bK[nt][kk] = *(const short8*)&kp[(nt * 16 + l15) * NW + kk * 32 + quad * 8];
    // residual x
    float xv[4][4];
    #pragma unroll
    for (int nt = 0; nt < 4; ++nt)
        #pragma unroll
        for (int r = 0; r < 4; ++r)
            xv[nt][r] = xp[(wv * 16 + quad * 4 + r) * NW + nt * 16 + l15];

    const floatx4 zero4 = {0.f, 0.f, 0.f, 0.f};

    // S = Q K^T (register-only; overlaps other waves' staging)
    floatx4 sA[4];
    #pragma unroll
    for (int nt = 0; nt < 4; ++nt) sA[nt] = zero4;
    #pragma unroll
    for (int kk = 0; kk < 2; ++kk)
        #pragma unroll
        for (int nt = 0; nt < 4; ++nt)
            sA[nt] = __builtin_amdgcn_mfma_f32_16x16x32_bf16(aQ[kk], bK[nt][kk], sA[nt], 0, 0, 0);

    // park V in LDS (natural layout)
    #pragma unroll
    for (int i = 0; i < 2; ++i)
        *(short8*)&Vn[vg[i]][vw0[i]] = vreg[i];
    __syncthreads();

    // transpose Vn -> Vs in LDS (row-broadcast reads, 2-way = free)
    {
        const int w = t & 63;
        const int gg0 = (t >> 6) * 2;
        #pragma unroll
        for (int i = 0; i < 2; ++i) {
            const int g8 = (gg0 + i) * 8;
            short8 vvv;
            #pragma unroll
            for (int j = 0; j < 8; ++j) vvv[j] = (short)Vn[g8 + j][w];
            *(short8*)&Vs[w][g8] = vvv;
        }
    }

    // row softmax (row = wv*16 + quad*4 + r); reductions inside each 16-lane quad
    float linv[4];
    #pragma unroll
    for (int r = 0; r < 4; ++r) {
        float m = sA[0][r];
        #pragma unroll
        for (int nt = 1; nt < 4; ++nt) m = fmaxf(m, sA[nt][r]);
        #pragma unroll
        for (int off = 1; off < 16; off <<= 1) m = fmaxf(m, __shfl_xor(m, off, 64));
        float e[4], sum = 0.f;
        #pragma unroll
        for (int nt = 0; nt < 4; ++nt) {
            e[nt] = __expf(sA[nt][r] - m);
            sum += e[nt];
        }
        #pragma unroll
        for (int off = 1; off < 16; off <<= 1) sum += __shfl_xor(sum, off, 64);
        linv[r] = 1.0f / sum;
        const int row = wv * 16 + quad * 4 + r;
        #pragma unroll
        for (int nt = 0; nt < 4; ++nt) Ps[row][nt * 16 + l15] = f2bf(e[nt]);
    }
    __syncthreads();

    // O = P * V
    short8 aP[2], bV[4][2];
    #pragma unroll
    for (int kk = 0; kk < 2; ++kk)
        aP[kk] = *(const short8*)&Ps[wv * 16 + l15][kk * 32 + quad * 8];
    #pragma unroll
    for (int nt = 0; nt < 4; ++nt)
        #pragma unroll
        for (int kk = 0; kk < 2; ++kk)
            bV[nt][kk] = *(const short8*)&Vs[nt * 16 + l15][kk * 32 + quad * 8];

    floatx4 o[4];
    #pragma unroll
    for (int nt = 0; nt < 4; ++nt) o[nt] = zero4;
    #pragma unroll
    for (int kk = 0; kk < 2; ++kk)
        #pragma unroll
        for (int nt = 0; nt < 4; ++nt)
            o[nt] = __builtin_amdgcn_mfma_f32_16x16x32_bf16(aP[kk], bV[nt][kk], o[nt], 0, 0, 0);

    #pragma unroll
    for (int nt = 0; nt < 4; ++nt)
        #pragma unroll
        for (int r = 0; r < 4; ++r) {
            const int row = wv * 16 + quad * 4 + r;
            const int col = nt * 16 + l15;
            op[row * NW + col] = o[nt][r] * linv[r] + xv[nt][r];
        }
}

// ---------------------------------------------------------------------------
extern "C" void kernel_launch(void* const* d_in, const int* in_sizes, int n_in,
                              void* d_out, int out_size, void* d_ws, size_t ws_size,
                              hipStream_t stream) {
    const float* x = (const float*)d_in[0];
    const float* ctx = (const float*)d_in[1];
    const float* wq = (const float*)d_in[2];
    const float* bq = (const float*)d_in[3];
    const float* wk = (const float*)d_in[4];
    const float* bk = (const float*)d_in[5];
    const float* wv = (const float*)d_in[6];
    const float* bv = (const float*)d_in[7];
    float* out = (float*)d_out;

    // ws layout: [0,40960) bf16 weights | [40960,41728) f32 biases | [65536,...) QKV
    ushort_t* wW = (ushort_t*)d_ws;
    float* wB = (float*)((char*)d_ws + 40960);

    const size_t perSlice = 3ull * NC_X * NHW * 2;   // Q+K+V bytes per slice = 1.5 MiB
    size_t avail = (ws_size > 65536) ? ws_size - 65536 : perSlice;
    int W = (int)(avail / perSlice);
    if (W > NS) W = NS;
    if (W < 1) W = 1;

    ushort_t* qws = (ushort_t*)((char*)d_ws + 65536);
    ushort_t* kws = qws + (size_t)NC_X * W * NHW;
    ushort_t* vws = kws + (size_t)NC_X * W * NHW;

    prep_kernel<<<dim3(32), dim3(256), 0, stream>>>(wq, bq, wk, bk, wv, bv, wW, wB);

    for (int s0 = 0; s0 < NS; s0 += W) {
        const int w = (NS - s0 < W) ? (NS - s0) : W;
        proj_kernel<<<dim3(64, w), dim3(256), 0, stream>>>(
            x, ctx, wW, wB, qws, kws, vws, s0, w);
        attn_kernel<<<dim3(64, w), dim3(256), 0, stream>>>(
            qws, kws, vws, x, out, s0, w);
    }
}